// Round 2
// baseline (442.907 us; speedup 1.0000x reference)
//
#include <hip/hip_runtime.h>
#include <hip/hip_bf16.h>
#include <math.h>
#include <stdint.h>

// Problem constants
#define BATCH 8
#define SEQ   2048
#define DMODEL 1024
#define GROUPS 2
#define VOCAB 320
#define NOUT  (GROUPS*VOCAB)   // 640
#define DG    (DMODEL/GROUPS)  // 512
#define NTOK  (BATCH*SEQ)      // 16384
#define NPAIR (NTOK*GROUPS)    // 32768

#define MARGIN 3.0f
#define CAP 65536              // candidate list capacity

typedef __attribute__((ext_vector_type(8))) short short8;
typedef __attribute__((ext_vector_type(4))) float f32x4;

__device__ __forceinline__ unsigned short f2bf(float f) {
    __hip_bfloat16 h = __float2bfloat16(f);   // RNE
    return *reinterpret_cast<unsigned short*>(&h);
}
__device__ __forceinline__ float bf2f(unsigned short u) {
    unsigned int x = ((unsigned int)u) << 16;
    return __uint_as_float(x);
}

// async global->LDS 16B copy (wave-uniform base + lane*16 on the LDS side)
__device__ __forceinline__ void async16(const void* gptr, const void* lptr) {
    __builtin_amdgcn_global_load_lds(
        (const __attribute__((address_space(1))) unsigned int*)(unsigned long long)(uintptr_t)gptr,
        (__attribute__((address_space(3))) unsigned int*)(unsigned int)(uintptr_t)lptr,
        16, 0, 0);
}

// ---------------------------------------------------------------------------
// Kernel 1: fp32 -> bf16 conversion of X and W
// ---------------------------------------------------------------------------
#define NX4 (NTOK*DMODEL/4)    // 4194304
#define NW4 (NOUT*DMODEL/4)    // 163840
__global__ __launch_bounds__(256) void convert_kernel(
    const float* __restrict__ X, const float* __restrict__ W,
    unsigned short* __restrict__ Xb, unsigned short* __restrict__ Wb)
{
    int i = blockIdx.x * 256 + threadIdx.x;
    const float4* src;
    ushort4* dst;
    int j;
    if (i < NX4) { src = (const float4*)X; dst = (ushort4*)Xb; j = i; }
    else         { src = (const float4*)W; dst = (ushort4*)Wb; j = i - NX4; if (j >= NW4) return; }
    float4 v = src[j];
    ushort4 u;
    u.x = f2bf(v.x); u.y = f2bf(v.y); u.z = f2bf(v.z); u.w = f2bf(v.w);
    dst[j] = u;
}

// ---------------------------------------------------------------------------
// Kernel 2: bf16 MFMA GEMM  logits[16384][640] (bf16) = Xb @ Wb^T + bias
// 128x128 tile, BK=32, global_load_lds staging, XOR-swizzled LDS chunks.
// LDS layout: 16B chunk for (row r, kchunk c in 0..3) lives at chunk index
//   p = 4r + (c ^ ((r>>1)&3))
// ---------------------------------------------------------------------------
__global__ __launch_bounds__(256) void gemm_bf16_kernel(
    const unsigned short* __restrict__ Xb,   // [16384][1024]
    const unsigned short* __restrict__ Wb,   // [640][1024]
    const float* __restrict__ bias,          // [640]
    unsigned short* __restrict__ logits)     // [16384][640] bf16
{
    __shared__ __align__(16) unsigned short As[128 * 32];  // 8 KB
    __shared__ __align__(16) unsigned short Bs[128 * 32];  // 8 KB

    const int tid  = threadIdx.x;
    const int lane = tid & 63;
    const int wave = tid >> 6;
    const int m0 = blockIdx.x * 128;
    const int n0 = blockIdx.y * 128;
    const int wm = (wave & 1) * 64;
    const int wn = (wave >> 1) * 64;

    f32x4 acc[4][4];
    #pragma unroll
    for (int a = 0; a < 4; a++)
        #pragma unroll
        for (int b = 0; b < 4; b++)
            acc[a][b] = (f32x4)0.0f;

    // staging: thread handles LDS chunk positions p = tid and tid+256 for A and B
    int aoff[2], boff[2], loff[2];
    #pragma unroll
    for (int j = 0; j < 2; j++) {
        int p = tid + j * 256;
        int r = p >> 2, s = p & 3;
        int c = s ^ ((r >> 1) & 3);
        aoff[j] = (m0 + r) * DMODEL + c * 8;   // bf16 element offset (+k0 later)
        boff[j] = (n0 + r) * DMODEL + c * 8;
        loff[j] = p * 8;                        // bf16 elements (16B chunks)
    }

    // fragment read offsets (bf16 elements): A row = wm+mi*16+(lane&15), kchunk h=lane>>4
    int afrag[4], bfrag[4];
    {
        int rho = lane & 15, h = lane >> 4;
        #pragma unroll
        for (int mi = 0; mi < 4; mi++) {
            int r = wm + mi * 16 + rho;
            afrag[mi] = (4 * r + (h ^ ((r >> 1) & 3))) * 8;
            int rn = wn + mi * 16 + rho;
            bfrag[mi] = (4 * rn + (h ^ ((rn >> 1) & 3))) * 8;
        }
    }

    for (int k0 = 0; k0 < DMODEL; k0 += 32) {
        #pragma unroll
        for (int j = 0; j < 2; j++) {
            async16(Xb + aoff[j] + k0, As + loff[j]);
            async16(Wb + boff[j] + k0, Bs + loff[j]);
        }
        __syncthreads();

        short8 af[4], bf[4];
        #pragma unroll
        for (int i = 0; i < 4; i++) {
            af[i] = *(const short8*)&As[afrag[i]];
            bf[i] = *(const short8*)&Bs[bfrag[i]];
        }
        #pragma unroll
        for (int mi = 0; mi < 4; mi++)
            #pragma unroll
            for (int ni = 0; ni < 4; ni++)
                acc[mi][ni] = __builtin_amdgcn_mfma_f32_16x16x32_bf16(
                    af[mi], bf[ni], acc[mi][ni], 0, 0, 0);
        __syncthreads();
    }

    // epilogue: bias add (fp32) + bf16 store
    const int colb = n0 + wn + (lane & 15);
    const int rowb = m0 + wm + (lane >> 4) * 4;
    float bv[4];
    #pragma unroll
    for (int ni = 0; ni < 4; ni++) bv[ni] = bias[colb + ni * 16];
    #pragma unroll
    for (int mi = 0; mi < 4; mi++)
        #pragma unroll
        for (int ni = 0; ni < 4; ni++)
            #pragma unroll
            for (int p = 0; p < 4; p++) {
                int row = rowb + mi * 16 + p;
                int col = colb + ni * 16;
                logits[row * NOUT + col] = f2bf(acc[mi][ni][p] + bv[ni]);
            }
}

// ---------------------------------------------------------------------------
// Kernel 3: per (token,group) wave: approx max + margin candidates
// ---------------------------------------------------------------------------
__global__ __launch_bounds__(256) void scan_kernel(
    const unsigned short* __restrict__ logits,
    float* __restrict__ out_idx,
    unsigned int* __restrict__ list,
    int* __restrict__ counter)
{
    const int wave = threadIdx.x >> 6;
    const int lane = threadIdx.x & 63;
    const int pair = blockIdx.x * 4 + wave;
    const int token = pair >> 1;
    const int g = pair & 1;

    const unsigned short* lp = logits + token * NOUT + g * VOCAB;
    float v[5];
    #pragma unroll
    for (int j = 0; j < 5; j++) v[j] = bf2f(lp[lane + 64 * j]);

    float best = v[0];
    int bi = lane;
    #pragma unroll
    for (int j = 1; j < 5; j++)
        if (v[j] > best) { best = v[j]; bi = lane + 64 * j; }

    #pragma unroll
    for (int off = 32; off > 0; off >>= 1) {
        float ov = __shfl_xor(best, off);
        int   oi = __shfl_xor(bi, off);
        if (ov > best || (ov == best && oi < bi)) { best = ov; bi = oi; }
    }

    const float thr = best - MARGIN;
    int cnt = 0;
    #pragma unroll
    for (int j = 0; j < 5; j++) cnt += (v[j] >= thr) ? 1 : 0;
    int tot = cnt;
    #pragma unroll
    for (int off = 32; off > 0; off >>= 1) tot += __shfl_xor(tot, off);

    if (tot == 1) {
        if (lane == 0) out_idx[pair] = (float)bi;
    } else {
        if (lane == 0) out_idx[pair] = -1.0f;
        #pragma unroll
        for (int j = 0; j < 5; j++) {
            if (v[j] >= thr) {
                int pos = atomicAdd(counter, 1);
                if (pos < CAP)
                    list[pos] = ((unsigned int)token << 10) | ((unsigned int)g << 9)
                              | (unsigned int)(lane + 64 * j);
            }
        }
    }
}

// ---------------------------------------------------------------------------
// Kernel 4: exact fp32 rescore of candidates (ascending-k fmaf chain ==
// round-1's proven-exact order). Winner via order-preserving atomicMax.
// ---------------------------------------------------------------------------
__global__ __launch_bounds__(256) void rescore_kernel(
    const float* __restrict__ X, const float* __restrict__ W,
    const float* __restrict__ bias,
    const unsigned int* __restrict__ list,
    const int* __restrict__ counter,
    unsigned long long* __restrict__ slots)
{
    int i = blockIdx.x * 256 + threadIdx.x;
    int n = *counter; if (n > CAP) n = CAP;
    if (i >= n) return;

    unsigned int e = list[i];
    int token = e >> 10;
    int g = (e >> 9) & 1;
    int v = e & 511;

    const float4* xr = (const float4*)(X + (size_t)token * DMODEL);
    const float4* wr = (const float4*)(W + (size_t)(g * VOCAB + v) * DMODEL);
    float acc = 0.0f;
    #pragma unroll 4
    for (int k = 0; k < DMODEL / 4; k++) {
        float4 a = xr[k], b = wr[k];
        acc = fmaf(a.x, b.x, acc);
        acc = fmaf(a.y, b.y, acc);
        acc = fmaf(a.z, b.z, acc);
        acc = fmaf(a.w, b.w, acc);
    }
    float logit = acc + bias[g * VOCAB + v];

    unsigned int ub = __float_as_uint(logit);
    unsigned int key32 = (ub & 0x80000000u) ? ~ub : (ub | 0x80000000u);
    unsigned long long key = ((unsigned long long)key32 << 32)
                           | (unsigned int)(511 - v);   // smaller v wins ties
    atomicMax(&slots[token * 2 + g], key);
}

// ---------------------------------------------------------------------------
// Kernel 5: gather codevectors, finalize ambiguous idx, histogram
// one block per token; threads 0..127 group 0, 128..255 group 1
// ---------------------------------------------------------------------------
__global__ __launch_bounds__(256) void gather_kernel(
    const float* __restrict__ cb,
    const unsigned long long* __restrict__ slots,
    float* __restrict__ out, float* __restrict__ out_idx,
    int* __restrict__ hist)
{
    const int token = blockIdx.x;
    const int t = threadIdx.x;
    const int g = t >> 7;
    const int l = t & 127;

    float idxf = out_idx[token * 2 + g];
    int v;
    if (idxf < -0.5f) {
        unsigned long long key = slots[token * 2 + g];
        v = 511 - (int)(key & 0xFFFFFFFFull);
    } else {
        v = (int)idxf;
    }
    if (l == 0) {
        if (idxf < -0.5f) out_idx[token * 2 + g] = (float)v;
        atomicAdd(&hist[g * VOCAB + v], 1);
    }
    float4 val = ((const float4*)(cb + (size_t)(g * VOCAB + v) * DG))[l];
    ((float4*)(out + (size_t)token * DMODEL + g * DG))[l] = val;
}

// ---------------------------------------------------------------------------
// Kernel 6: diversity loss scalar
// ---------------------------------------------------------------------------
__global__ __launch_bounds__(256) void diversity_kernel(
    const int* __restrict__ hist, float* __restrict__ out_scalar)
{
    __shared__ float s0[256], s1[256];
    const int tid = threadIdx.x;
    float a0 = 0.0f, a1 = 0.0f;
    for (int i = tid; i < NOUT; i += 256) {
        float m = (float)hist[i] * (1.0f / (float)NTOK);
        float t = m * logf(m + 1e-7f);
        if (i < VOCAB) a0 += t; else a1 += t;
    }
    s0[tid] = a0; s1[tid] = a1;
    __syncthreads();
    for (int s = 128; s > 0; s >>= 1) {
        if (tid < s) { s0[tid] += s0[tid + s]; s1[tid] += s1[tid + s]; }
        __syncthreads();
    }
    if (tid == 0) {
        float perplexity = expf(-s0[0]) + expf(-s1[0]);
        *out_scalar = ((float)NOUT - perplexity) / (float)NOUT * 0.1f;
    }
}

// ---------------------------------------------------------------------------
extern "C" void kernel_launch(void* const* d_in, const int* in_sizes, int n_in,
                              void* d_out, int out_size, void* d_ws, size_t ws_size,
                              hipStream_t stream) {
    const float* X    = (const float*)d_in[0];  // [8,2048,1024]
    const float* W    = (const float*)d_in[1];  // [640,1024]
    const float* bias = (const float*)d_in[2];  // [640]
    const float* cb   = (const float*)d_in[3];  // [1,640,512]

    float* out      = (float*)d_out;                   // [16384*1024]
    float* out_idx  = out + (size_t)NTOK * DMODEL;     // [32768]
    float* out_loss = out_idx + NPAIR;                 // [1]

    // workspace layout
    char* p = (char*)d_ws;
    unsigned short* Xb = (unsigned short*)p;           p += (size_t)NTOK * DMODEL * 2;   // 32 MB
    unsigned short* Wb = (unsigned short*)p;           p += (size_t)NOUT * DMODEL * 2;   // 1.25 MB
    unsigned short* logits = (unsigned short*)p;       p += (size_t)NTOK * NOUT * 2;     // 20 MB
    unsigned long long* slots = (unsigned long long*)p; p += (size_t)NPAIR * 8;          // 256 KB
    unsigned int* list = (unsigned int*)p;             p += (size_t)CAP * 4;             // 256 KB
    int* counter = (int*)p;                            p += 256;
    int* hist = (int*)p;                               p += NOUT * 4;

    // zero slots | list | counter | hist in one shot (contiguous)
    size_t zbytes = (size_t)NPAIR * 8 + (size_t)CAP * 4 + 256 + NOUT * 4;
    hipMemsetAsync(slots, 0, zbytes, stream);

    convert_kernel<<<(NX4 + NW4) / 256, 256, 0, stream>>>(X, W, Xb, Wb);

    dim3 ggrid(NTOK / 128, NOUT / 128);  // 128 x 5
    gemm_bf16_kernel<<<ggrid, 256, 0, stream>>>(Xb, Wb, bias, logits);

    scan_kernel<<<NPAIR / 4, 256, 0, stream>>>(logits, out_idx, list, counter);

    rescore_kernel<<<CAP / 256, 256, 0, stream>>>(X, W, bias, list, counter, slots);

    gather_kernel<<<NTOK, 256, 0, stream>>>(cb, slots, out, out_idx, hist);

    diversity_kernel<<<1, 256, 0, stream>>>(hist, out_loss);
}